// Round 10
// baseline (159.895 us; speedup 1.0000x reference)
//
#include <hip/hip_runtime.h>
#include <hip/hip_bf16.h>

#define S_LEN 2048
#define E_DIM 1024
#define NH 16
#define DH 64

typedef __bf16 v8bf __attribute__((ext_vector_type(8)));
typedef __bf16 v4bf __attribute__((ext_vector_type(4)));
typedef float f32x4 __attribute__((ext_vector_type(4)));
typedef unsigned short u16x4 __attribute__((ext_vector_type(4)));
typedef unsigned short u16x8 __attribute__((ext_vector_type(8)));

// Static device scratch (fully rewritten each launch)
__device__ __align__(16) unsigned short g_Xb[S_LEN * E_DIM];       // x as bf16 [s][e]
__device__ __align__(16) unsigned short g_WT[3 * E_DIM * E_DIM];   // [3072][1024] K-major Wq|Wk|Wv (bf16)
__device__ __align__(16) unsigned short g_WoT[E_DIM * E_DIM];      // [1024][1024] Wo^T (K-major, bf16)
__device__ __align__(16) unsigned short g_Qb[NH * S_LEN * DH];     // [h][s][d] row-major
// FRAGMENT-MAJOR layouts: every flash wave-load is fully contiguous.
// K (K=32 A/B-frag): [h][t/16][d/32][m16][quad4][8]  (1KB per 16t x 32d frag-pair)
// V (K=16 A-frag):   [h][t/16][d/16][m16][quad4][4]  (512B per 16t x 16d frag)
__device__ __align__(16) unsigned short g_Kb[NH * S_LEN * DH];
__device__ __align__(16) unsigned short g_Vt[NH * DH * S_LEN];
__device__ __align__(16) unsigned short g_AO[S_LEN * E_DIM];       // [s][h*64+d] (bf16)

__device__ inline unsigned short f2bf(float f) {
    unsigned int u = __float_as_uint(f);
    u += 0x7FFF + ((u >> 16) & 1);   // RNE
    return (unsigned short)(u >> 16);
}
__device__ inline f32x4 mfma16(v8bf a, v8bf b, f32x4 c) {
    return __builtin_amdgcn_mfma_f32_16x16x32_bf16(a, b, c, 0, 0, 0);
}
// K=16 bf16 MFMA (2-reg A/B). Name differs across ROCm versions; 3-way guard
// (compiled + harness-passed in rounds 4 and 9).
__device__ inline f32x4 mfma16k16(v4bf a, v4bf b, f32x4 c) {
#if __has_builtin(__builtin_amdgcn_mfma_f32_16x16x16_bf16)
    return __builtin_amdgcn_mfma_f32_16x16x16_bf16(a, b, c, 0, 0, 0);
#elif __has_builtin(__builtin_amdgcn_mfma_f32_16x16x16bf16_1k)
    typedef short s4v __attribute__((ext_vector_type(4)));
    union UA { v4bf v; s4v s; };
    UA ua, ub; ua.v = a; ub.v = b;
    return __builtin_amdgcn_mfma_f32_16x16x16bf16_1k(ua.s, ub.s, c, 0, 0, 0);
#else
    asm("v_mfma_f32_16x16x16_bf16 %0, %1, %2, %0" : "+v"(c) : "v"(a), "v"(b));
    return c;
#endif
}

// async global->LDS, 16B per lane; LDS dest = wave-uniform base + lane*16
typedef __attribute__((address_space(3))) unsigned int lds_u32;
typedef __attribute__((address_space(1))) const unsigned int glb_u32;
__device__ inline void async_cp16(const unsigned short* g, unsigned short* l) {
    __builtin_amdgcn_global_load_lds((glb_u32*)g, (lds_u32*)l, 16, 0, 0);
}

// ---------------- prep: convert x + transpose weights (vectorized) ----------------
__global__ __launch_bounds__(256) void prep(const float* __restrict__ X,
                                            const float* __restrict__ Wq,
                                            const float* __restrict__ Wk,
                                            const float* __restrict__ Wv,
                                            const float* __restrict__ Wo) {
    __shared__ __align__(16) unsigned short lds[64 * 72];
    const int b = blockIdx.x;
    const int t = threadIdx.x;
    if (b < 2048) {
        int i = b * 256 + t;
        f32x4 v = reinterpret_cast<const f32x4*>(X)[i];
        u16x4 o = {f2bf(v.x), f2bf(v.y), f2bf(v.z), f2bf(v.w)};
        reinterpret_cast<u16x4*>(g_Xb)[i] = o;
    } else if (b < 2304) {
        int bb = b - 2048;
        const int h = bb >> 4;
        const int e0 = (bb & 15) * 64;
        const float* srcs[3] = {Wq, Wk, Wv};
#pragma unroll
        for (int tn = 0; tn < 3; tn++) {
            const float* W = srcs[tn] + h * 65536;
#pragma unroll
            for (int p = 0; p < 4; p++) {
                int e = p * 16 + (t >> 4);
                int d = (t & 15) * 4;
                f32x4 v = *reinterpret_cast<const f32x4*>(&W[(e0 + e) * 64 + d]);
                lds[(d + 0) * 72 + e] = f2bf(v.x);
                lds[(d + 1) * 72 + e] = f2bf(v.y);
                lds[(d + 2) * 72 + e] = f2bf(v.z);
                lds[(d + 3) * 72 + e] = f2bf(v.w);
            }
            __syncthreads();
#pragma unroll
            for (int p = 0; p < 2; p++) {
                int d = p * 32 + (t >> 3);
                int ec = (t & 7) * 8;
                u16x8 o = *reinterpret_cast<const u16x8*>(&lds[d * 72 + ec]);
                *reinterpret_cast<u16x8*>(&g_WT[(tn * 1024 + h * 64 + d) * E_DIM + e0 + ec]) = o;
            }
            __syncthreads();
        }
    } else {
        int bb = b - 2304;
        const int f0 = (bb >> 4) * 64;
        const int e0 = (bb & 15) * 64;
#pragma unroll
        for (int p = 0; p < 4; p++) {
            int f = p * 16 + (t >> 4);
            int e = (t & 15) * 4;
            f32x4 v = *reinterpret_cast<const f32x4*>(&Wo[(f0 + f) * E_DIM + e0 + e]);
            lds[(e + 0) * 72 + f] = f2bf(v.x);
            lds[(e + 1) * 72 + f] = f2bf(v.y);
            lds[(e + 2) * 72 + f] = f2bf(v.z);
            lds[(e + 3) * 72 + f] = f2bf(v.w);
        }
        __syncthreads();
#pragma unroll
        for (int p = 0; p < 2; p++) {
            int e = p * 32 + (t >> 3);
            int fc = (t & 7) * 8;
            u16x8 o = *reinterpret_cast<const u16x8*>(&lds[e * 72 + fc]);
            *reinterpret_cast<u16x8*>(&g_WoT[(e0 + e) * E_DIM + f0 + fc]) = o;
        }
    }
}

// ---------------- QKV projection GEMM (128s x 64n, grid (16,48)) ----------------
// Round-9 version (unchanged): round-2 pipeline + fragment-major K/V stores.
//   K: idx(t,d) = (t>>4)*1024 + (d>>5)*512 + (t&15)*32 + ((d>>3)&3)*8 + (d&7)
//   V: idx(d,t) = (t>>4)*1024 + (d>>4)*256 + (d&15)*16 + (t&15)
__global__ __launch_bounds__(256) void qkv_gemm(const float* __restrict__ bq,
                                                const float* __restrict__ bk,
                                                const float* __restrict__ bv) {
    __shared__ __align__(16) unsigned short lds[24576];   // 48KB: 2 x (lA 128x64 + lB 64x64)
    const int t = threadIdx.x;
    const int wave = t >> 6;
    const int lane = t & 63;
    const int m = lane & 15, quad = lane >> 4;
    const int s0 = blockIdx.x * 128;
    const int n0 = blockIdx.y * 64;

    const int rl = t >> 3;
    const int cx = (t & 7) ^ (rl & 7);
    const int axor = m & 7;

    f32x4 acc[2][4];
#pragma unroll
    for (int i = 0; i < 2; i++)
#pragma unroll
        for (int j = 0; j < 4; j++) acc[i][j] = (f32x4){0.f, 0.f, 0.f, 0.f};

    const unsigned short* gA = g_Xb + (s0 + rl) * E_DIM + cx * 8;
    const unsigned short* gB = g_WT + (n0 + rl) * E_DIM + cx * 8;

    auto stage = [&](int k0, int buf) {
        unsigned short* lA = lds + buf * 12288;
        unsigned short* lB = lA + 8192;
        const unsigned short* ga = gA + k0;
        async_cp16(ga,              lA + wave * 512);
        async_cp16(ga + 32 * E_DIM, lA + 2048 + wave * 512);
        async_cp16(ga + 64 * E_DIM, lA + 4096 + wave * 512);
        async_cp16(ga + 96 * E_DIM, lA + 6144 + wave * 512);
        const unsigned short* gb = gB + k0;
        async_cp16(gb,              lB + wave * 512);
        async_cp16(gb + 32 * E_DIM, lB + 2048 + wave * 512);
    };

    stage(0, 0);
    __syncthreads();                                     // drains vmcnt(0): buf0 ready
    int buf = 0;
    for (int k0 = 0; k0 < E_DIM; k0 += 64) {
        if (k0 + 64 < E_DIM) stage(k0 + 64, buf ^ 1);    // overlap loads with compute
        const unsigned short* lA = lds + buf * 12288;
        const unsigned short* lB = lA + 8192;
        const unsigned short* lAr0 = lA + (wave * 32 + m) * 64;
        const unsigned short* lAr1 = lAr0 + 16 * 64;
#pragma unroll
        for (int ks = 0; ks < 2; ks++) {
            const int ch = ((ks * 4 + quad) ^ axor) * 8;
            v8bf a0 = *reinterpret_cast<const v8bf*>(lAr0 + ch);
            v8bf a1 = *reinterpret_cast<const v8bf*>(lAr1 + ch);
#pragma unroll
            for (int j = 0; j < 4; j++) {
                v8bf bfr = *reinterpret_cast<const v8bf*>(lB + (j * 16 + m) * 64 + ch);
                acc[0][j] = mfma16(a0, bfr, acc[0][j]);
                acc[1][j] = mfma16(a1, bfr, acc[1][j]);
            }
        }
        __syncthreads();                                 // single barrier: next buf ready
        buf ^= 1;
    }

    const int tensor = n0 >> 10;
    const int nn0 = n0 & 1023;
    const int hh = nn0 >> 6;
    const float* bb = tensor == 0 ? bq : (tensor == 1 ? bk : bv);
    float bias[4];
#pragma unroll
    for (int j = 0; j < 4; j++) bias[j] = bb[nn0 + j * 16 + m];

    if (tensor < 2) {
#pragma unroll
        for (int i = 0; i < 2; i++)
#pragma unroll
            for (int j = 0; j < 4; j++)
#pragma unroll
                for (int r = 0; r < 4; r++) {
                    int sl = wave * 32 + i * 16 + quad * 4 + r;
                    int nl = j * 16 + m;
                    lds[sl * 72 + nl] = f2bf(acc[i][j][r] + bias[j]);
                }
        __syncthreads();
        if (tensor == 0) {
            unsigned short* dst = g_Qb + (hh * S_LEN + s0) * DH;
#pragma unroll
            for (int p = 0; p < 4; p++) {
                int row = p * 32 + (t >> 3);
                int c = t & 7;
                u16x8 v = *reinterpret_cast<const u16x8*>(&lds[row * 72 + c * 8]);
                *reinterpret_cast<u16x8*>(&dst[row * DH + c * 8]) = v;
            }
        } else {
            // K fragment-major store
            unsigned short* dst = g_Kb + hh * S_LEN * DH;
            const int tb0 = s0 >> 4;
#pragma unroll
            for (int p = 0; p < 4; p++) {
                int row = p * 32 + (t >> 3);
                int c = t & 7;
                u16x8 v = *reinterpret_cast<const u16x8*>(&lds[row * 72 + c * 8]);
                int idx = (tb0 + (row >> 4)) * 1024 + (c >> 2) * 512 + (row & 15) * 32 + (c & 3) * 8;
                *reinterpret_cast<u16x8*>(&dst[idx]) = v;
            }
        }
    } else {
#pragma unroll
        for (int i = 0; i < 2; i++)
#pragma unroll
            for (int j = 0; j < 4; j++)
#pragma unroll
                for (int r = 0; r < 4; r++) {
                    int sl = wave * 32 + i * 16 + quad * 4 + r;
                    int nl = j * 16 + m;
                    lds[nl * 136 + sl] = f2bf(acc[i][j][r] + bias[j]);
                }
        __syncthreads();
        // V K=16-A-frag store
        unsigned short* dst = g_Vt + hh * S_LEN * DH;
#pragma unroll
        for (int p = 0; p < 4; p++) {
            int nl = p * 16 + (t >> 4);                  // d
            int sc = t & 15;                             // t-octet
            u16x8 v = *reinterpret_cast<const u16x8*>(&lds[nl * 136 + sc * 8]);
            int idx = ((s0 >> 4) + (sc >> 1)) * 1024 + (nl >> 4) * 256 + (nl & 15) * 16 + (sc & 1) * 8;
            *reinterpret_cast<u16x8*>(&dst[idx]) = v;
        }
    }
}

// ---------------- causal flash attention (64 q-rows/block: K/V traffic halved) --
// r9's zero-LDS swapped-QK math, but each block now owns 64 q-rows (4 sub-tiles
// of 16) so every K/V fragment load is reused 4x (was 2x). Logical K/V cache
// traffic 545MB -> ~280MB -- r8/r9 showed flash is L2/L3-service-bound (all
// schedule variants floor at the same dur; only memory-path changes move it).
// Grid 512 = exactly 2 blocks/CU; dispatch pairing {B, 31-B} keeps per-CU work
// constant. K prefetch right after sub3's QK (last kf use); V prefetch at iter
// end; one-iter-ahead distance as verified in r8/r9.
__global__ __launch_bounds__(256) void flash_attn() {
    __shared__ __align__(16) float comb[256 * 20];       // 20KB epilogue-only
    const int t = threadIdx.x;
    const int wave = t >> 6, lane = t & 63;
    const int m = lane & 15, quad = lane >> 4;
    const int h = blockIdx.x & 15;
    const int Tp = blockIdx.x >> 4;                      // 0..31
    const int B = (Tp < 16) ? Tp : 47 - Tp;              // long blocks dispatched 2nd half
    const int s0 = B * 64;

    const unsigned short* Qh = g_Qb + h * S_LEN * DH;
    const unsigned short* Kh = g_Kb + h * S_LEN * DH;    // fragment-major (K=32)
    const unsigned short* Vh = g_Vt + h * S_LEN * DH;    // fragment-major (K=16 A)
    const int ko = m * 32 + quad * 8;                    // K frag lane offset
    const int vo = m * 16 + quad * 4;                    // V frag lane offset
    const int tq = quad * 4;

    // Q as B-operand (K=32) for 4 q-sub-tiles: lane m = q-row, k = d = quad*8+j
    v8bf aq[4][2];
#pragma unroll
    for (int sub = 0; sub < 4; sub++) {
        const unsigned short* qp = Qh + (s0 + sub * 16 + m) * DH + quad * 8;
        aq[sub][0] = *reinterpret_cast<const v8bf*>(qp);
        aq[sub][1] = *reinterpret_cast<const v8bf*>(qp + 32);
    }

    f32x4 o[4][4];                                       // [sub][dt] O^T partials
#pragma unroll
    for (int sub = 0; sub < 4; sub++)
#pragma unroll
        for (int dt = 0; dt < 4; dt++) o[sub][dt] = (f32x4){0.f,0.f,0.f,0.f};
    float l[4] = {0.f, 0.f, 0.f, 0.f};

    const float SC = 0.125f * 1.44269504088896f;         // 1/sqrt(64) * log2(e)
    const int tEnd = s0 + 64;

    int t0 = wave * 64;
    v8bf kf[4][2];                                       // K A-frags (rows=t), 64 cols
    v4bf vf[4][4];                                       // V^T K=16 A-frags [dt][ct]
    if (t0 < tEnd) {
        const unsigned short* kb = Kh + t0 * 64 + ko;
#pragma unroll
        for (int ct = 0; ct < 4; ct++) {
            kf[ct][0] = *reinterpret_cast<const v8bf*>(kb + ct * 1024);
            kf[ct][1] = *reinterpret_cast<const v8bf*>(kb + ct * 1024 + 512);
        }
        const unsigned short* vb = Vh + t0 * 64 + vo;
#pragma unroll
        for (int dt = 0; dt < 4; dt++)
#pragma unroll
            for (int ct = 0; ct < 4; ct++)
                vf[dt][ct] = *reinterpret_cast<const v4bf*>(vb + ct * 1024 + dt * 256);
    }

    for (; t0 < tEnd; t0 += 256) {
        const int t1 = t0 + 256;
        // sub 0 first .. sub 3 last: sub3 is ALWAYS live (t0 <= s0+63), so kf's
        // final use is sub3's QK -> prefetch K right there.
#pragma unroll
        for (int sub = 0; sub < 4; sub++) {
            const int qb = s0 + sub * 16;                // q-row base of this sub-tile
            if (t0 <= qb + 15) {                         // wave-uniform liveness
                // QK^T (swapped: A=K rows=t, B=Q cols=q)
                __builtin_amdgcn_s_setprio(1);
                f32x4 s[4];
#pragma unroll
                for (int ct = 0; ct < 4; ct++) {
                    s[ct] = (f32x4){0.f,0.f,0.f,0.f};
                    s[ct] = mfma16(kf[ct][0], aq[sub][0], s[ct]);
                    s[ct] = mfma16(kf[ct][1], aq[sub][1], s[ct]);
                }
                __builtin_amdgcn_s_setprio(0);
                if (sub == 3 && t1 < tEnd) {             // kf dead: prefetch next K
                    const unsigned short* kb = Kh + t1 * 64 + ko;
#pragma unroll
                    for (int ct = 0; ct < 4; ct++) {
                        kf[ct][0] = *reinterpret_cast<const v8bf*>(kb + ct * 1024);
                        kf[ct][1] = *reinterpret_cast<const v8bf*>(kb + ct * 1024 + 512);
                    }
                }
                // mask, exp2, l partial, pack to PV B-operand
                v4bf pt[4];
#pragma unroll
                for (int ct = 0; ct < 4; ct++) {
                    const int tb = t0 + ct * 16 + tq;    // lane's t base (r adds 0..3)
                    if (t0 + ct * 16 + 15 > qb) {
#pragma unroll
                        for (int r = 0; r < 4; r++)
                            if (tb + r > qb + m) s[ct][r] = -3e38f;
                    }
#pragma unroll
                    for (int r = 0; r < 4; r++)
                        s[ct][r] = __builtin_amdgcn_exp2f(s[ct][r] * SC);
                    l[sub] += s[ct][0] + s[ct][1] + s[ct][2] + s[ct][3];
                    __hip_bfloat162 b01 = __float22bfloat162_rn(make_float2(s[ct][0], s[ct][1]));
                    __hip_bfloat162 b23 = __float22bfloat162_rn(make_float2(s[ct][2], s[ct][3]));
                    union { unsigned int u[2]; v4bf v; } pk;
                    pk.u[0] = *reinterpret_cast<unsigned int*>(&b01);
                    pk.u[1] = *reinterpret_cast<unsigned int*>(&b23);
                    pt[ct] = pk.v;
                }
                // PV: O^T += V^T x P^T
                __builtin_amdgcn_s_setprio(1);
#pragma unroll
                for (int dt = 0; dt < 4; dt++)
#pragma unroll
                    for (int ct = 0; ct < 4; ct++)
                        o[sub][dt] = mfma16k16(vf[dt][ct], pt[ct], o[sub][dt]);
                __builtin_amdgcn_s_setprio(0);
            }
        }
        // prefetch next chunk's V (all PVs consumed vf)
        if (t1 < tEnd) {
            const unsigned short* vb = Vh + t1 * 64 + vo;
#pragma unroll
            for (int dt = 0; dt < 4; dt++)
#pragma unroll
                for (int ct = 0; ct < 4; ct++)
                    vf[dt][ct] = *reinterpret_cast<const v4bf*>(vb + ct * 1024 + dt * 256);
        }
    }

    // ---- cross-wave combine: 4 phases (one per sub-tile), r9 pattern ----
    float* cw = comb + t * 20;
#pragma unroll
    for (int sub = 0; sub < 4; sub++) {
        if (sub) __syncthreads();                        // prev phase reads done
#pragma unroll
        for (int dt = 0; dt < 4; dt++) *reinterpret_cast<f32x4*>(cw + dt * 4) = o[sub][dt];
        cw[16] = l[sub];
        __syncthreads();
        f32x4 os = (f32x4){0.f,0.f,0.f,0.f};
        float ls = 0.f;
#pragma unroll
        for (int w = 0; w < 4; w++) {
            const float* cr = comb + (w * 64 + lane) * 20;
            os += *reinterpret_cast<const f32x4*>(cr + wave * 4);
#pragma unroll
            for (int q2 = 0; q2 < 4; q2++)
                ls += comb[(w * 64 + q2 * 16 + m) * 20 + 16];
        }
        float inv = 1.0f / ls;
        u16x4 ov = {f2bf(os[0] * inv), f2bf(os[1] * inv), f2bf(os[2] * inv), f2bf(os[3] * inv)};
        *reinterpret_cast<u16x4*>(&g_AO[(s0 + sub * 16 + m) * E_DIM + h * 64 + wave * 16 + quad * 4]) = ov;
    }
}

// ---------------- output projection (128s x 64n, grid (16,16)) ----------------
__global__ __launch_bounds__(256) void out_gemm(const float* __restrict__ bo,
                                                float* __restrict__ OUT) {
    __shared__ __align__(16) unsigned short lds[24576];   // 48KB: 2 x (lA 128x64 + lB 64x64)
    const int t = threadIdx.x;
    const int wave = t >> 6;
    const int lane = t & 63;
    const int m = lane & 15, quad = lane >> 4;
    const int s0 = blockIdx.x * 128;
    const int n0 = blockIdx.y * 64;

    const int rl = t >> 3;
    const int cx = (t & 7) ^ (rl & 7);
    const int axor = m & 7;

    f32x4 acc[2][4];
#pragma unroll
    for (int i = 0; i < 2; i++)
#pragma unroll
        for (int j = 0; j < 4; j++) acc[i][j] = (f32x4){0.f, 0.f, 0.f, 0.f};

    const unsigned short* gA = g_AO + (s0 + rl) * E_DIM + cx * 8;
    const unsigned short* gB = g_WoT + (n0 + rl) * E_DIM + cx * 8;

    auto stage = [&](int k0, int buf) {
        unsigned short* lA = lds + buf * 12288;
        unsigned short* lB = lA + 8192;
        const unsigned short* ga = gA + k0;
        async_cp16(ga,              lA + wave * 512);
        async_cp16(ga + 32 * E_DIM, lA + 2048 + wave * 512);
        async_cp16(ga + 64 * E_DIM, lA + 4096 + wave * 512);
        async_cp16(ga + 96 * E_DIM, lA + 6144 + wave * 512);
        const unsigned short* gb = gB + k0;
        async_cp16(gb,              lB + wave * 512);
        async_cp16(gb + 32 * E_DIM, lB + 2048 + wave * 512);
    };

    stage(0, 0);
    __syncthreads();
    int buf = 0;
    for (int k0 = 0; k0 < E_DIM; k0 += 64) {
        if (k0 + 64 < E_DIM) stage(k0 + 64, buf ^ 1);
        const unsigned short* lA = lds + buf * 12288;
        const unsigned short* lB = lA + 8192;
        const unsigned short* lAr0 = lA + (wave * 32 + m) * 64;
        const unsigned short* lAr1 = lAr0 + 16 * 64;
#pragma unroll
        for (int ks = 0; ks < 2; ks++) {
            const int ch = ((ks * 4 + quad) ^ axor) * 8;
            v8bf a0 = *reinterpret_cast<const v8bf*>(lAr0 + ch);
            v8bf a1 = *reinterpret_cast<const v8bf*>(lAr1 + ch);
#pragma unroll
            for (int j = 0; j < 4; j++) {
                v8bf bfr = *reinterpret_cast<const v8bf*>(lB + (j * 16 + m) * 64 + ch);
                acc[0][j] = mfma16(a0, bfr, acc[0][j]);
                acc[1][j] = mfma16(a1, bfr, acc[1][j]);
            }
        }
        __syncthreads();
        buf ^= 1;
    }
#pragma unroll
    for (int i = 0; i < 2; i++)
#pragma unroll
        for (int j = 0; j < 4; j++) {
            int e = n0 + j * 16 + m;
            float bias = bo[e];
#pragma unroll
            for (int r = 0; r < 4; r++) {
                int s = s0 + wave * 32 + i * 16 + quad * 4 + r;
                OUT[s * E_DIM + e] = acc[i][j][r] + bias;
            }
        }
}

extern "C" void kernel_launch(void* const* d_in, const int* in_sizes, int n_in,
                              void* d_out, int out_size, void* d_ws, size_t ws_size,
                              hipStream_t stream) {
    (void)in_sizes; (void)n_in; (void)out_size; (void)d_ws; (void)ws_size;
    const float* x  = (const float*)d_in[0];
    const float* Wq = (const float*)d_in[1];
    const float* bq = (const float*)d_in[2];
    const float* Wk = (const float*)d_in[3];
    const float* bk = (const float*)d_in[4];
    const float* Wv = (const float*)d_in[5];
    const float* bv = (const float*)d_in[6];
    const float* Wo = (const float*)d_in[7];
    const float* bo = (const float*)d_in[8];
    float* out = (float*)d_out;

    hipLaunchKernelGGL(prep,       dim3(2560),   dim3(256), 0, stream, x, Wq, Wk, Wv, Wo);
    hipLaunchKernelGGL(qkv_gemm,   dim3(16, 48), dim3(256), 0, stream, bq, bk, bv);
    hipLaunchKernelGGL(flash_attn, dim3(512),    dim3(256), 0, stream);
    hipLaunchKernelGGL(out_gemm,   dim3(16, 16), dim3(256), 0, stream, bo, out);
}

// Round 11
// 154.683 us; speedup vs baseline: 1.0337x; 1.0337x over previous
//
#include <hip/hip_runtime.h>
#include <hip/hip_bf16.h>

#define S_LEN 2048
#define E_DIM 1024
#define NH 16
#define DH 64

typedef __bf16 v8bf __attribute__((ext_vector_type(8)));
typedef float f32x4 __attribute__((ext_vector_type(4)));
typedef unsigned short u16x4 __attribute__((ext_vector_type(4)));
typedef unsigned short u16x8 __attribute__((ext_vector_type(8)));

// Static device scratch (fully rewritten each launch)
__device__ __align__(16) unsigned short g_Xb[S_LEN * E_DIM];       // x as bf16 [s][e]
__device__ __align__(16) unsigned short g_WT[3 * E_DIM * E_DIM];   // [3072][1024] K-major Wq|Wk|Wv (bf16)
__device__ __align__(16) unsigned short g_WoT[E_DIM * E_DIM];      // [1024][1024] Wo^T (K-major, bf16)
__device__ __align__(16) unsigned short g_Qb[NH * S_LEN * DH];     // [h][s][d] row-major
// FRAGMENT-MAJOR layouts (round 8, best measured): flash's MFMA fragment loads
// are 1KB fully-contiguous per wave instruction (were 16 scattered 64B txns).
__device__ __align__(16) unsigned short g_Kb[NH * S_LEN * DH];     // [h][t/16][d/32][m16][quad4][8]
__device__ __align__(16) unsigned short g_Vt[NH * DH * S_LEN];     // [h][t/64][d/16][t32][m16][quad4][8]
__device__ __align__(16) unsigned short g_AO[S_LEN * E_DIM];       // [s][h*64+d] (bf16)

__device__ inline unsigned short f2bf(float f) {
    unsigned int u = __float_as_uint(f);
    u += 0x7FFF + ((u >> 16) & 1);   // RNE
    return (unsigned short)(u >> 16);
}
__device__ inline f32x4 mfma16(v8bf a, v8bf b, f32x4 c) {
    return __builtin_amdgcn_mfma_f32_16x16x32_bf16(a, b, c, 0, 0, 0);
}

// async global->LDS, 16B per lane; LDS dest = wave-uniform base + lane*16
typedef __attribute__((address_space(3))) unsigned int lds_u32;
typedef __attribute__((address_space(1))) const unsigned int glb_u32;
__device__ inline void async_cp16(const unsigned short* g, unsigned short* l) {
    __builtin_amdgcn_global_load_lds((glb_u32*)g, (lds_u32*)l, 16, 0, 0);
}

// ---------------- prep: convert x + transpose weights (vectorized) ----------------
__global__ __launch_bounds__(256) void prep(const float* __restrict__ X,
                                            const float* __restrict__ Wq,
                                            const float* __restrict__ Wk,
                                            const float* __restrict__ Wv,
                                            const float* __restrict__ Wo) {
    __shared__ __align__(16) unsigned short lds[64 * 72];
    const int b = blockIdx.x;
    const int t = threadIdx.x;
    if (b < 2048) {
        int i = b * 256 + t;
        f32x4 v = reinterpret_cast<const f32x4*>(X)[i];
        u16x4 o = {f2bf(v.x), f2bf(v.y), f2bf(v.z), f2bf(v.w)};
        reinterpret_cast<u16x4*>(g_Xb)[i] = o;
    } else if (b < 2304) {
        int bb = b - 2048;
        const int h = bb >> 4;
        const int e0 = (bb & 15) * 64;
        const float* srcs[3] = {Wq, Wk, Wv};
#pragma unroll
        for (int tn = 0; tn < 3; tn++) {
            const float* W = srcs[tn] + h * 65536;
#pragma unroll
            for (int p = 0; p < 4; p++) {
                int e = p * 16 + (t >> 4);
                int d = (t & 15) * 4;
                f32x4 v = *reinterpret_cast<const f32x4*>(&W[(e0 + e) * 64 + d]);
                lds[(d + 0) * 72 + e] = f2bf(v.x);
                lds[(d + 1) * 72 + e] = f2bf(v.y);
                lds[(d + 2) * 72 + e] = f2bf(v.z);
                lds[(d + 3) * 72 + e] = f2bf(v.w);
            }
            __syncthreads();
#pragma unroll
            for (int p = 0; p < 2; p++) {
                int d = p * 32 + (t >> 3);
                int ec = (t & 7) * 8;
                u16x8 o = *reinterpret_cast<const u16x8*>(&lds[d * 72 + ec]);
                *reinterpret_cast<u16x8*>(&g_WT[(tn * 1024 + h * 64 + d) * E_DIM + e0 + ec]) = o;
            }
            __syncthreads();
        }
    } else {
        int bb = b - 2304;
        const int f0 = (bb >> 4) * 64;
        const int e0 = (bb & 15) * 64;
#pragma unroll
        for (int p = 0; p < 4; p++) {
            int f = p * 16 + (t >> 4);
            int e = (t & 15) * 4;
            f32x4 v = *reinterpret_cast<const f32x4*>(&Wo[(f0 + f) * E_DIM + e0 + e]);
            lds[(e + 0) * 72 + f] = f2bf(v.x);
            lds[(e + 1) * 72 + f] = f2bf(v.y);
            lds[(e + 2) * 72 + f] = f2bf(v.z);
            lds[(e + 3) * 72 + f] = f2bf(v.w);
        }
        __syncthreads();
#pragma unroll
        for (int p = 0; p < 2; p++) {
            int e = p * 32 + (t >> 3);
            int fc = (t & 7) * 8;
            u16x8 o = *reinterpret_cast<const u16x8*>(&lds[e * 72 + fc]);
            *reinterpret_cast<u16x8*>(&g_WoT[(e0 + e) * E_DIM + f0 + fc]) = o;
        }
    }
}

// ---------------- QKV projection GEMM (128s x 64n, grid (16,48)) ----------------
// Round-2 pipeline; epilogue stores K and V in fragment-major layout (round 8).
//   K: idx(t,d) = (t>>4)*1024 + (d>>5)*512 + (t&15)*32 + ((d>>3)&3)*8 + (d&7)
//   V: idx(d,t) = ((t>>6)*4+(d>>4))*1024 + ((t>>5)&1)*512 + (d&15)*32 + ((t>>3)&3)*8 + (t&7)
__global__ __launch_bounds__(256) void qkv_gemm(const float* __restrict__ bq,
                                                const float* __restrict__ bk,
                                                const float* __restrict__ bv) {
    __shared__ __align__(16) unsigned short lds[24576];   // 48KB: 2 x (lA 128x64 + lB 64x64)
    const int t = threadIdx.x;
    const int wave = t >> 6;
    const int lane = t & 63;
    const int m = lane & 15, quad = lane >> 4;
    const int s0 = blockIdx.x * 128;
    const int n0 = blockIdx.y * 64;

    const int rl = t >> 3;
    const int cx = (t & 7) ^ (rl & 7);
    const int axor = m & 7;

    f32x4 acc[2][4];
#pragma unroll
    for (int i = 0; i < 2; i++)
#pragma unroll
        for (int j = 0; j < 4; j++) acc[i][j] = (f32x4){0.f, 0.f, 0.f, 0.f};

    const unsigned short* gA = g_Xb + (s0 + rl) * E_DIM + cx * 8;
    const unsigned short* gB = g_WT + (n0 + rl) * E_DIM + cx * 8;

    auto stage = [&](int k0, int buf) {
        unsigned short* lA = lds + buf * 12288;
        unsigned short* lB = lA + 8192;
        const unsigned short* ga = gA + k0;
        async_cp16(ga,              lA + wave * 512);
        async_cp16(ga + 32 * E_DIM, lA + 2048 + wave * 512);
        async_cp16(ga + 64 * E_DIM, lA + 4096 + wave * 512);
        async_cp16(ga + 96 * E_DIM, lA + 6144 + wave * 512);
        const unsigned short* gb = gB + k0;
        async_cp16(gb,              lB + wave * 512);
        async_cp16(gb + 32 * E_DIM, lB + 2048 + wave * 512);
    };

    stage(0, 0);
    __syncthreads();                                     // drains vmcnt(0): buf0 ready
    int buf = 0;
    for (int k0 = 0; k0 < E_DIM; k0 += 64) {
        if (k0 + 64 < E_DIM) stage(k0 + 64, buf ^ 1);    // overlap loads with compute
        const unsigned short* lA = lds + buf * 12288;
        const unsigned short* lB = lA + 8192;
        const unsigned short* lAr0 = lA + (wave * 32 + m) * 64;
        const unsigned short* lAr1 = lAr0 + 16 * 64;
#pragma unroll
        for (int ks = 0; ks < 2; ks++) {
            const int ch = ((ks * 4 + quad) ^ axor) * 8;
            v8bf a0 = *reinterpret_cast<const v8bf*>(lAr0 + ch);
            v8bf a1 = *reinterpret_cast<const v8bf*>(lAr1 + ch);
#pragma unroll
            for (int j = 0; j < 4; j++) {
                v8bf bfr = *reinterpret_cast<const v8bf*>(lB + (j * 16 + m) * 64 + ch);
                acc[0][j] = mfma16(a0, bfr, acc[0][j]);
                acc[1][j] = mfma16(a1, bfr, acc[1][j]);
            }
        }
        __syncthreads();                                 // single barrier: next buf ready
        buf ^= 1;
    }

    const int tensor = n0 >> 10;
    const int nn0 = n0 & 1023;
    const int hh = nn0 >> 6;
    const float* bb = tensor == 0 ? bq : (tensor == 1 ? bk : bv);
    float bias[4];
#pragma unroll
    for (int j = 0; j < 4; j++) bias[j] = bb[nn0 + j * 16 + m];

    if (tensor < 2) {
#pragma unroll
        for (int i = 0; i < 2; i++)
#pragma unroll
            for (int j = 0; j < 4; j++)
#pragma unroll
                for (int r = 0; r < 4; r++) {
                    int sl = wave * 32 + i * 16 + quad * 4 + r;
                    int nl = j * 16 + m;
                    lds[sl * 72 + nl] = f2bf(acc[i][j][r] + bias[j]);
                }
        __syncthreads();
        if (tensor == 0) {
            unsigned short* dst = g_Qb + (hh * S_LEN + s0) * DH;
#pragma unroll
            for (int p = 0; p < 4; p++) {
                int row = p * 32 + (t >> 3);
                int c = t & 7;
                u16x8 v = *reinterpret_cast<const u16x8*>(&lds[row * 72 + c * 8]);
                *reinterpret_cast<u16x8*>(&dst[row * DH + c * 8]) = v;
            }
        } else {
            // K fragment-major store
            unsigned short* dst = g_Kb + hh * S_LEN * DH;
            const int tb0 = s0 >> 4;
#pragma unroll
            for (int p = 0; p < 4; p++) {
                int row = p * 32 + (t >> 3);
                int c = t & 7;
                u16x8 v = *reinterpret_cast<const u16x8*>(&lds[row * 72 + c * 8]);
                int idx = (tb0 + (row >> 4)) * 1024 + (c >> 2) * 512 + (row & 15) * 32 + (c & 3) * 8;
                *reinterpret_cast<u16x8*>(&dst[idx]) = v;
            }
        }
    } else {
#pragma unroll
        for (int i = 0; i < 2; i++)
#pragma unroll
            for (int j = 0; j < 4; j++)
#pragma unroll
                for (int r = 0; r < 4; r++) {
                    int sl = wave * 32 + i * 16 + quad * 4 + r;
                    int nl = j * 16 + m;
                    lds[nl * 136 + sl] = f2bf(acc[i][j][r] + bias[j]);
                }
        __syncthreads();
        // V fragment-major store (s0 = t-range base, 128 cols; nl = d)
        unsigned short* dst = g_Vt + hh * S_LEN * DH;
        const int tc0 = s0 >> 6;
#pragma unroll
        for (int p = 0; p < 4; p++) {
            int nl = p * 16 + (t >> 4);
            int sc = t & 15;
            u16x8 v = *reinterpret_cast<const u16x8*>(&lds[nl * 136 + sc * 8]);
            int idx = (tc0 + (sc >> 3)) * 4096 + (nl >> 4) * 1024 + ((sc >> 2) & 1) * 512
                    + (nl & 15) * 32 + (sc & 3) * 8;
            *reinterpret_cast<u16x8*>(&dst[idx]) = v;
        }
    }
}

// ---------------- causal flash attention (round-8 verbatim: best measured) ----
// r2 schedule + single LDS drain + fragment-major K/V (1KB coalesced wave
// loads). Best measured configuration: total 155.58us, flash ~30us.
// Mechanism ledger: coalescing (r8) -12us; schedule rewrites (r3/r4/r5/r7),
// LDS-removal (r9), traffic-halving (r10) all null/negative.
__global__ __launch_bounds__(256) void flash_attn() {
    __shared__ __align__(16) unsigned char smem[24576];
    unsigned short* plds = (unsigned short*)smem;        // per-wave 32x72 P region
    float* comb = (float*)smem;                          // [256][24] combine area
    const int t = threadIdx.x;
    const int wave = t >> 6, lane = t & 63;
    const int m = lane & 15, quad = lane >> 4;
    const int h = blockIdx.x & 15;
    const int Tp = blockIdx.x >> 4;                      // 0..63
    const int qq = Tp >> 4, tt = Tp & 15;
    const int T = (qq == 0) ? tt : (qq == 1) ? 31 - tt : (qq == 2) ? 32 + tt : 63 - tt;
    const int s0 = T * 32;

    const unsigned short* Qh = g_Qb + h * S_LEN * DH;
    const unsigned short* Kh = g_Kb + h * S_LEN * DH;    // fragment-major
    const unsigned short* Vh = g_Vt + h * S_LEN * DH;    // fragment-major
    const int lo = m * 32 + quad * 8;                    // per-lane offset within 1KB fragment tile

    v8bf aqA0 = *reinterpret_cast<const v8bf*>(Qh + (s0 + m) * DH + quad * 8);
    v8bf aqA1 = *reinterpret_cast<const v8bf*>(Qh + (s0 + m) * DH + 32 + quad * 8);
    v8bf aqB0 = *reinterpret_cast<const v8bf*>(Qh + (s0 + 16 + m) * DH + quad * 8);
    v8bf aqB1 = *reinterpret_cast<const v8bf*>(Qh + (s0 + 16 + m) * DH + 32 + quad * 8);

    f32x4 oA[4], oB[4];
#pragma unroll
    for (int i = 0; i < 4; i++) { oA[i] = (f32x4){0.f,0.f,0.f,0.f}; oB[i] = (f32x4){0.f,0.f,0.f,0.f}; }
    f32x4 laccA = (f32x4){0.f,0.f,0.f,0.f}, laccB = (f32x4){0.f,0.f,0.f,0.f};

    v8bf ones;
#pragma unroll
    for (int i = 0; i < 8; i++) ones[i] = (__bf16)1.0f;

    const float SC = 0.125f * 1.44269504088896f;         // 1/sqrt(64) * log2(e)
    unsigned short* pw = plds + wave * 2304;             // this wave's P region (32x72)
    const int tEnd = s0 + 32;

    int t0 = wave * 64;
    v8bf kf[4][2], vf[4][2];
    if (t0 < tEnd) {
        const unsigned short* kb = Kh + t0 * 64 + lo;
#pragma unroll
        for (int ct = 0; ct < 4; ct++) {
            kf[ct][0] = *reinterpret_cast<const v8bf*>(kb + ct * 1024);
            kf[ct][1] = *reinterpret_cast<const v8bf*>(kb + ct * 1024 + 512);
        }
        const unsigned short* vb = Vh + t0 * 64 + lo;
#pragma unroll
        for (int dt = 0; dt < 4; dt++) {
            vf[dt][0] = *reinterpret_cast<const v8bf*>(vb + dt * 1024);
            vf[dt][1] = *reinterpret_cast<const v8bf*>(vb + dt * 1024 + 512);
        }
    }

    for (; t0 < tEnd; t0 += 256) {
        const bool doA = (t0 < s0 + 16);                 // wave-uniform
        const int t1 = t0 + 256;

        // QK^T for both row sub-tiles
        __builtin_amdgcn_s_setprio(1);
        f32x4 sB[4];
#pragma unroll
        for (int ct = 0; ct < 4; ct++) {
            sB[ct] = (f32x4){0.f,0.f,0.f,0.f};
            sB[ct] = mfma16(aqB0, kf[ct][0], sB[ct]);
            sB[ct] = mfma16(aqB1, kf[ct][1], sB[ct]);
        }
        f32x4 sA[4];
        if (doA) {
#pragma unroll
            for (int ct = 0; ct < 4; ct++) {
                sA[ct] = (f32x4){0.f,0.f,0.f,0.f};
                sA[ct] = mfma16(aqA0, kf[ct][0], sA[ct]);
                sA[ct] = mfma16(aqA1, kf[ct][1], sA[ct]);
            }
        }
        __builtin_amdgcn_s_setprio(0);

        // prefetch next iter's K directly into kf (coalesced 1KB per load)
        if (t1 < tEnd) {
            const unsigned short* kb = Kh + t1 * 64 + lo;
#pragma unroll
            for (int ct = 0; ct < 4; ct++) {
                kf[ct][0] = *reinterpret_cast<const v8bf*>(kb + ct * 1024);
                kf[ct][1] = *reinterpret_cast<const v8bf*>(kb + ct * 1024 + 512);
            }
        }

        // ---- mask + exp + pack + LDS-write for BOTH sub-tiles (single drain) ----
#pragma unroll
        for (int ct = 0; ct < 4; ct++) {
            int colbase = t0 + ct * 16;
            int col = colbase + m;
            if (colbase + 15 > s0 + 16) {
#pragma unroll
                for (int r = 0; r < 4; r++)
                    if (col > s0 + 16 + quad * 4 + r) sB[ct][r] = -3e38f;
            }
        }
#pragma unroll
        for (int ct = 0; ct < 4; ct++) {
#pragma unroll
            for (int r = 0; r < 4; r++)
                sB[ct][r] = __builtin_amdgcn_exp2f(sB[ct][r] * SC);
            __hip_bfloat162 p01 = __float22bfloat162_rn(make_float2(sB[ct][0], sB[ct][1]));
            __hip_bfloat162 p23 = __float22bfloat162_rn(make_float2(sB[ct][2], sB[ct][3]));
            unsigned short* pb = pw + (16 + quad * 4) * 72 + ct * 16 + m;
            pb[0]   = *reinterpret_cast<unsigned short*>(&p01.x);
            pb[72]  = *reinterpret_cast<unsigned short*>(&p01.y);
            pb[144] = *reinterpret_cast<unsigned short*>(&p23.x);
            pb[216] = *reinterpret_cast<unsigned short*>(&p23.y);
        }
        if (doA) {
#pragma unroll
            for (int ct = 0; ct < 4; ct++) {
                int colbase = t0 + ct * 16;
                int col = colbase + m;
                if (colbase + 15 > s0) {
#pragma unroll
                    for (int r = 0; r < 4; r++)
                        if (col > s0 + quad * 4 + r) sA[ct][r] = -3e38f;
                }
            }
#pragma unroll
            for (int ct = 0; ct < 4; ct++) {
#pragma unroll
                for (int r = 0; r < 4; r++)
                    sA[ct][r] = __builtin_amdgcn_exp2f(sA[ct][r] * SC);
                __hip_bfloat162 p01 = __float22bfloat162_rn(make_float2(sA[ct][0], sA[ct][1]));
                __hip_bfloat162 p23 = __float22bfloat162_rn(make_float2(sA[ct][2], sA[ct][3]));
                unsigned short* pa = pw + (quad * 4) * 72 + ct * 16 + m;
                pa[0]   = *reinterpret_cast<unsigned short*>(&p01.x);
                pa[72]  = *reinterpret_cast<unsigned short*>(&p01.y);
                pa[144] = *reinterpret_cast<unsigned short*>(&p23.x);
                pa[216] = *reinterpret_cast<unsigned short*>(&p23.y);
            }
        }
        __builtin_amdgcn_s_waitcnt(0xC07F);              // ONE lgkmcnt(0) for both sub-tiles

        // ---- PV for both sub-tiles ----
        {
            v8bf apB0 = *reinterpret_cast<const v8bf*>(pw + (16 + m) * 72 + quad * 8);
            v8bf apB1 = *reinterpret_cast<const v8bf*>(pw + (16 + m) * 72 + 32 + quad * 8);
            __builtin_amdgcn_s_setprio(1);
#pragma unroll
            for (int dt = 0; dt < 4; dt++) {
                oB[dt] = mfma16(apB0, vf[dt][0], oB[dt]);
                oB[dt] = mfma16(apB1, vf[dt][1], oB[dt]);
            }
            laccB = mfma16(apB0, ones, laccB);           // l partial: rows match O's C-layout
            laccB = mfma16(apB1, ones, laccB);
            __builtin_amdgcn_s_setprio(0);
        }
        if (doA) {
            v8bf apA0 = *reinterpret_cast<const v8bf*>(pw + m * 72 + quad * 8);
            v8bf apA1 = *reinterpret_cast<const v8bf*>(pw + m * 72 + 32 + quad * 8);
            __builtin_amdgcn_s_setprio(1);
#pragma unroll
            for (int dt = 0; dt < 4; dt++) {
                oA[dt] = mfma16(apA0, vf[dt][0], oA[dt]);
                oA[dt] = mfma16(apA1, vf[dt][1], oA[dt]);
            }
            laccA = mfma16(apA0, ones, laccA);
            laccA = mfma16(apA1, ones, laccA);
            __builtin_amdgcn_s_setprio(0);
        }

        // prefetch next iter's V into vf (coalesced 1KB per load)
        if (t1 < tEnd) {
            const unsigned short* vb = Vh + t1 * 64 + lo;
#pragma unroll
            for (int dt = 0; dt < 4; dt++) {
                vf[dt][0] = *reinterpret_cast<const v8bf*>(vb + dt * 1024);
                vf[dt][1] = *reinterpret_cast<const v8bf*>(vb + dt * 1024 + 512);
            }
        }
    }

    // ---- 2-phase cross-wave combine (o,l additive; l already per-row) ----
    float* cw = comb + (wave * 64 + lane) * 24;
    __syncthreads();                                     // P regions dead
#pragma unroll
    for (int dt = 0; dt < 4; dt++) *reinterpret_cast<f32x4*>(cw + dt * 4) = oA[dt];
    *reinterpret_cast<f32x4*>(cw + 16) = laccA;
    __syncthreads();
    {
        f32x4 oAt = (f32x4){0.f,0.f,0.f,0.f}, l4 = (f32x4){0.f,0.f,0.f,0.f};
#pragma unroll
        for (int w = 0; w < 4; w++) {
            const float* cr = comb + (w * 64 + lane) * 24;
            oAt += *reinterpret_cast<const f32x4*>(cr + wave * 4);
            l4  += *reinterpret_cast<const f32x4*>(cr + 16);
        }
#pragma unroll
        for (int r = 0; r < 4; r++) {
            float inv = 1.0f / l4[r];
            g_AO[(s0 + quad * 4 + r) * E_DIM + h * 64 + wave * 16 + m] = f2bf(oAt[r] * inv);
        }
    }
    __syncthreads();
#pragma unroll
    for (int dt = 0; dt < 4; dt++) *reinterpret_cast<f32x4*>(cw + dt * 4) = oB[dt];
    *reinterpret_cast<f32x4*>(cw + 16) = laccB;
    __syncthreads();
    {
        f32x4 oBt = (f32x4){0.f,0.f,0.f,0.f}, l4 = (f32x4){0.f,0.f,0.f,0.f};
#pragma unroll
        for (int w = 0; w < 4; w++) {
            const float* cr = comb + (w * 64 + lane) * 24;
            oBt += *reinterpret_cast<const f32x4*>(cr + wave * 4);
            l4  += *reinterpret_cast<const f32x4*>(cr + 16);
        }
#pragma unroll
        for (int r = 0; r < 4; r++) {
            float inv = 1.0f / l4[r];
            g_AO[(s0 + 16 + quad * 4 + r) * E_DIM + h * 64 + wave * 16 + m] = f2bf(oBt[r] * inv);
        }
    }
}

// ---------------- output projection (128s x 64n, grid (16,16)) ----------------
__global__ __launch_bounds__(256) void out_gemm(const float* __restrict__ bo,
                                                float* __restrict__ OUT) {
    __shared__ __align__(16) unsigned short lds[24576];   // 48KB: 2 x (lA 128x64 + lB 64x64)
    const int t = threadIdx.x;
    const int wave = t >> 6;
    const int lane = t & 63;
    const int m = lane & 15, quad = lane >> 4;
    const int s0 = blockIdx.x * 128;
    const int n0 = blockIdx.y * 64;

    const int rl = t >> 3;
    const int cx = (t & 7) ^ (rl & 7);
    const int axor = m & 7;

    f32x4 acc[2][4];
#pragma unroll
    for (int i = 0; i < 2; i++)
#pragma unroll
        for (int j = 0; j < 4; j++) acc[i][j] = (f32x4){0.f, 0.f, 0.f, 0.f};

    const unsigned short* gA = g_AO + (s0 + rl) * E_DIM + cx * 8;
    const unsigned short* gB = g_WoT + (n0 + rl) * E_DIM + cx * 8;

    auto stage = [&](int k0, int buf) {
        unsigned short* lA = lds + buf * 12288;
        unsigned short* lB = lA + 8192;
        const unsigned short* ga = gA + k0;
        async_cp16(ga,              lA + wave * 512);
        async_cp16(ga + 32 * E_DIM, lA + 2048 + wave * 512);
        async_cp16(ga + 64 * E_DIM, lA + 4096 + wave * 512);
        async_cp16(ga + 96 * E_DIM, lA + 6144 + wave * 512);
        const unsigned short* gb = gB + k0;
        async_cp16(gb,              lB + wave * 512);
        async_cp16(gb + 32 * E_DIM, lB + 2048 + wave * 512);
    };

    stage(0, 0);
    __syncthreads();
    int buf = 0;
    for (int k0 = 0; k0 < E_DIM; k0 += 64) {
        if (k0 + 64 < E_DIM) stage(k0 + 64, buf ^ 1);
        const unsigned short* lA = lds + buf * 12288;
        const unsigned short* lB = lA + 8192;
        const unsigned short* lAr0 = lA + (wave * 32 + m) * 64;
        const unsigned short* lAr1 = lAr0 + 16 * 64;
#pragma unroll
        for (int ks = 0; ks < 2; ks++) {
            const int ch = ((ks * 4 + quad) ^ axor) * 8;
            v8bf a0 = *reinterpret_cast<const v8bf*>(lAr0 + ch);
            v8bf a1 = *reinterpret_cast<const v8bf*>(lAr1 + ch);
#pragma unroll
            for (int j = 0; j < 4; j++) {
                v8bf bfr = *reinterpret_cast<const v8bf*>(lB + (j * 16 + m) * 64 + ch);
                acc[0][j] = mfma16(a0, bfr, acc[0][j]);
                acc[1][j] = mfma16(a1, bfr, acc[1][j]);
            }
        }
        __syncthreads();
        buf ^= 1;
    }
#pragma unroll
    for (int i = 0; i < 2; i++)
#pragma unroll
        for (int j = 0; j < 4; j++) {
            int e = n0 + j * 16 + m;
            float bias = bo[e];
#pragma unroll
            for (int r = 0; r < 4; r++) {
                int s = s0 + wave * 32 + i * 16 + quad * 4 + r;
                OUT[s * E_DIM + e] = acc[i][j][r] + bias;
            }
        }
}

extern "C" void kernel_launch(void* const* d_in, const int* in_sizes, int n_in,
                              void* d_out, int out_size, void* d_ws, size_t ws_size,
                              hipStream_t stream) {
    (void)in_sizes; (void)n_in; (void)out_size; (void)d_ws; (void)ws_size;
    const float* x  = (const float*)d_in[0];
    const float* Wq = (const float*)d_in[1];
    const float* bq = (const float*)d_in[2];
    const float* Wk = (const float*)d_in[3];
    const float* bk = (const float*)d_in[4];
    const float* Wv = (const float*)d_in[5];
    const float* bv = (const float*)d_in[6];
    const float* Wo = (const float*)d_in[7];
    const float* bo = (const float*)d_in[8];
    float* out = (float*)d_out;

    hipLaunchKernelGGL(prep,       dim3(2560),   dim3(256), 0, stream, x, Wq, Wk, Wv, Wo);
    hipLaunchKernelGGL(qkv_gemm,   dim3(16, 48), dim3(256), 0, stream, bq, bk, bv);
    hipLaunchKernelGGL(flash_attn, dim3(1024),   dim3(256), 0, stream);
    hipLaunchKernelGGL(out_gemm,   dim3(16, 16), dim3(256), 0, stream, bo, out);
}